// Round 1
// baseline (555.272 us; speedup 1.0000x reference)
//
#include <hip/hip_runtime.h>

#define Bv 2
#define Nv 5000
#define Cv 768
#define Hv 12
#define Dv 64
#define Ev 160000
#define ETOT (Ev + Nv)   // 165000 (edges + self loops)
#define HD 768
#define NEG 0.2f

// monotonic float<->uint encoding for atomicMax on floats (incl. negatives)
__device__ __forceinline__ unsigned enc_f(float f) {
  unsigned u = __float_as_uint(f);
  return (u & 0x80000000u) ? ~u : (u | 0x80000000u);
}
__device__ __forceinline__ float dec_f(unsigned u) {
  return (u & 0x80000000u) ? __uint_as_float(u & 0x7fffffffu) : __uint_as_float(~u);
}

// ---------------- GEMM: h[M,768] = x[M,768] @ W[768,768] (f32 tiled) -------
#define BM 64
#define BN 64
#define BK 16
__global__ __launch_bounds__(256) void k_gemm(const float* __restrict__ A,
                                              const float* __restrict__ W,
                                              float* __restrict__ C, int M) {
  __shared__ float As[BK][BM + 1];
  __shared__ float Bs[BK][BN + 1];
  const int t = threadIdx.x;
  const int tx = t % 16, ty = t / 16;
  const int bm = blockIdx.y * BM, bn = blockIdx.x * BN;
  float acc[4][4] = {};
  for (int k0 = 0; k0 < Cv; k0 += BK) {
    for (int l = t; l < BM * BK; l += 256) {
      int kk = l % BK, m = l / BK;
      int row = bm + m;
      As[kk][m] = (row < M) ? A[(size_t)row * Cv + k0 + kk] : 0.0f;
    }
    for (int l = t; l < BK * BN; l += 256) {
      int col = l % BN, kk = l / BN;
      Bs[kk][col] = W[(size_t)(k0 + kk) * HD + bn + col];
    }
    __syncthreads();
#pragma unroll
    for (int kk = 0; kk < BK; ++kk) {
      float a[4], b[4];
#pragma unroll
      for (int i = 0; i < 4; ++i) a[i] = As[kk][ty * 4 + i];
#pragma unroll
      for (int j = 0; j < 4; ++j) b[j] = Bs[kk][tx * 4 + j];
#pragma unroll
      for (int i = 0; i < 4; ++i)
#pragma unroll
        for (int j = 0; j < 4; ++j) acc[i][j] = fmaf(a[i], b[j], acc[i][j]);
    }
    __syncthreads();
  }
  for (int i = 0; i < 4; ++i) {
    int row = bm + ty * 4 + i;
    if (row < M) {
      for (int j = 0; j < 4; ++j)
        C[(size_t)row * HD + bn + tx * 4 + j] = acc[i][j];
    }
  }
}

// ---------------- attention dots: a_src/a_dst[b,n,h] = <h row, att row> ----
__global__ void k_att(const float* __restrict__ h, const float* __restrict__ att_src,
                      const float* __restrict__ att_dst, float* __restrict__ asrc,
                      float* __restrict__ adst) {
  int w = (blockIdx.x * blockDim.x + threadIdx.x) >> 6;  // one wave per (b,n,h)
  int lane = threadIdx.x & 63;
  if (w >= Bv * Nv * Hv) return;
  int hh = w % Hv;
  int bn = w / Hv;
  float hv = h[(size_t)bn * HD + hh * Dv + lane];
  float vs = hv * att_src[hh * Dv + lane];
  float vd = hv * att_dst[hh * Dv + lane];
  for (int off = 32; off; off >>= 1) {
    vs += __shfl_xor(vs, off);
    vd += __shfl_xor(vd, off);
  }
  if (lane == 0) { asrc[w] = vs; adst[w] = vd; }
}

// ---------------- CSR build ------------------------------------------------
__global__ void k_count(const int* __restrict__ ei, int* __restrict__ counts) {
  int e = blockIdx.x * blockDim.x + threadIdx.x;
  if (e >= ETOT) return;
  int dst = (e < Ev) ? ei[Ev + e] : (e - Ev);
  atomicAdd(&counts[dst], 1);
}

__global__ void k_scan(const int* __restrict__ counts, int* __restrict__ offsets) {
  __shared__ int part[256];
  const int t = threadIdx.x;
  const int chunk = (Nv + 255) / 256;  // 20
  int begin = t * chunk;
  int end = begin + chunk;
  if (end > Nv) end = Nv;
  if (begin > Nv) begin = Nv;
  int s = 0;
  for (int i = begin; i < end; ++i) s += counts[i];
  part[t] = s;
  __syncthreads();
  for (int off = 1; off < 256; off <<= 1) {
    int v = (t >= off) ? part[t - off] : 0;
    __syncthreads();
    part[t] += v;
    __syncthreads();
  }
  int run = (t == 0) ? 0 : part[t - 1];
  for (int i = begin; i < end; ++i) {
    offsets[i] = run;
    run += counts[i];
  }
  if (t == 0) offsets[Nv] = ETOT;
}

__global__ void k_scatter(const int* __restrict__ ei, const int* __restrict__ offsets,
                          int* __restrict__ cursor, int* __restrict__ csr) {
  int e = blockIdx.x * blockDim.x + threadIdx.x;
  if (e >= ETOT) return;
  int dst = (e < Ev) ? ei[Ev + e] : (e - Ev);
  int pos = atomicAdd(&cursor[dst], 1);
  csr[offsets[dst] + pos] = e;
}

// ---------------- softmax: segment max then exp+denominator ---------------
__global__ void k_emax(const int* __restrict__ ei, const float* __restrict__ asrc,
                       const float* __restrict__ adst, unsigned* __restrict__ menc) {
  int idx = blockIdx.x * blockDim.x + threadIdx.x;
  if (idx >= ETOT * Bv * Hv) return;
  int e = idx / (Bv * Hv);
  int r = idx % (Bv * Hv);
  int b = r / Hv, hh = r % Hv;
  int src = (e < Ev) ? ei[e] : (e - Ev);
  int dst = (e < Ev) ? ei[Ev + e] : (e - Ev);
  float v = asrc[((size_t)b * Nv + src) * Hv + hh] + adst[((size_t)b * Nv + dst) * Hv + hh];
  v = (v > 0.f) ? v : NEG * v;
  atomicMax(&menc[((size_t)b * Nv + dst) * Hv + hh], enc_f(v));
}

__global__ void k_ex(const int* __restrict__ ei, const float* __restrict__ asrc,
                     const float* __restrict__ adst, const unsigned* __restrict__ menc,
                     float* __restrict__ denom, float* __restrict__ exbuf) {
  int idx = blockIdx.x * blockDim.x + threadIdx.x;
  if (idx >= ETOT * Bv * Hv) return;
  int e = idx / (Bv * Hv);
  int r = idx % (Bv * Hv);
  int b = r / Hv, hh = r % Hv;
  int src = (e < Ev) ? ei[e] : (e - Ev);
  int dst = (e < Ev) ? ei[Ev + e] : (e - Ev);
  size_t di = ((size_t)b * Nv + dst) * Hv + hh;
  float v = asrc[((size_t)b * Nv + src) * Hv + hh] + adst[di];
  v = (v > 0.f) ? v : NEG * v;
  float ex = expf(v - dec_f(menc[di]));
  exbuf[idx] = ex;  // layout [e][b][h] == idx
  atomicAdd(&denom[di], ex);
}

// ---------------- aggregation: out[b,n,:] = sum_e alpha * h[b,src,:] ------
__global__ __launch_bounds__(256) void k_agg(const float* __restrict__ h,
                                             const int* __restrict__ ei,
                                             const int* __restrict__ offsets,
                                             const int* __restrict__ csr,
                                             const float* __restrict__ exbuf,
                                             const float* __restrict__ denom,
                                             const float* __restrict__ bias,
                                             float* __restrict__ out) {
  const int bn = blockIdx.x;  // b*Nv + n
  const int b = bn / Nv, n = bn % Nv;
  const int t = threadIdx.x;
  __shared__ float s_den[Hv];
  __shared__ float s_ex[16][Hv];
  __shared__ int s_src[16];
  if (t < Hv) s_den[t] = denom[(size_t)bn * Hv + t];
  __syncthreads();
  const int h0 = t >> 6;  // thread covers dims t, t+256, t+512 -> heads h0, h0+4, h0+8
  float invd[3];
  invd[0] = 1.0f / (s_den[h0] + 1e-16f);
  invd[1] = 1.0f / (s_den[h0 + 4] + 1e-16f);
  invd[2] = 1.0f / (s_den[h0 + 8] + 1e-16f);
  float acc[3] = {0.f, 0.f, 0.f};
  const int beg = offsets[n], endv = offsets[n + 1];
  for (int base = beg; base < endv; base += 16) {
    const int cnt = min(16, endv - base);
    if (t < cnt) {
      int e = csr[base + t];
      s_src[t] = (e < Ev) ? ei[e] : (e - Ev);
    }
    if (t < cnt * Hv) {
      int i = t / Hv, hh = t % Hv;
      int e = csr[base + i];
      s_ex[i][hh] = exbuf[(size_t)e * (Bv * Hv) + b * Hv + hh];
    }
    __syncthreads();
    for (int i = 0; i < cnt; ++i) {
      const float* hp = h + ((size_t)b * Nv + s_src[i]) * HD;
      float w0 = s_ex[i][h0] * invd[0];
      float w1 = s_ex[i][h0 + 4] * invd[1];
      float w2 = s_ex[i][h0 + 8] * invd[2];
      acc[0] = fmaf(w0, hp[t], acc[0]);
      acc[1] = fmaf(w1, hp[t + 256], acc[1]);
      acc[2] = fmaf(w2, hp[t + 512], acc[2]);
    }
    __syncthreads();
  }
  size_t ob = (size_t)bn * HD;
  out[ob + t] = acc[0] + bias[t];
  out[ob + t + 256] = acc[1] + bias[t + 256];
  out[ob + t + 512] = acc[2] + bias[t + 512];
}

extern "C" void kernel_launch(void* const* d_in, const int* in_sizes, int n_in,
                              void* d_out, int out_size, void* d_ws, size_t ws_size,
                              hipStream_t stream) {
  const float* x = (const float*)d_in[0];
  const float* W = (const float*)d_in[1];
  const float* att_src = (const float*)d_in[2];
  const float* att_dst = (const float*)d_in[3];
  const float* bias = (const float*)d_in[4];
  const int* ei = (const int*)d_in[5];
  float* out = (float*)d_out;

  // workspace layout (floats unless noted)
  float* ws = (float*)d_ws;
  float* h = ws;                                       // B*N*HD = 7,680,000
  float* asrc = h + (size_t)Bv * Nv * HD;              // 120,000
  float* adst = asrc + (size_t)Bv * Nv * Hv;           // 120,000
  unsigned* menc = (unsigned*)(adst + (size_t)Bv * Nv * Hv);  // 120,000
  float* denom = (float*)(menc + (size_t)Bv * Nv * Hv);       // 120,000
  float* exbuf = denom + (size_t)Bv * Nv * Hv;         // ETOT*B*H = 3,960,000
  int* counts = (int*)(exbuf + (size_t)ETOT * Bv * Hv);  // Nv
  int* cursor = counts + Nv;                           // Nv
  int* offsets = cursor + Nv;                          // Nv+1
  int* csr = offsets + Nv + 1;                         // ETOT

  // zero menc+denom (contiguous) and counts+cursor (contiguous)
  hipMemsetAsync(menc, 0, sizeof(float) * 2 * (size_t)Bv * Nv * Hv, stream);
  hipMemsetAsync(counts, 0, sizeof(int) * 2 * Nv, stream);

  const int M = Bv * Nv;
  dim3 gg(HD / BN, (M + BM - 1) / BM);
  k_gemm<<<gg, 256, 0, stream>>>(x, W, h, M);
  k_att<<<(Bv * Nv * Hv + 3) / 4, 256, 0, stream>>>(h, att_src, att_dst, asrc, adst);
  k_count<<<(ETOT + 255) / 256, 256, 0, stream>>>(ei, counts);
  k_scan<<<1, 256, 0, stream>>>(counts, offsets);
  k_scatter<<<(ETOT + 255) / 256, 256, 0, stream>>>(ei, offsets, cursor, csr);
  k_emax<<<(ETOT * Bv * Hv + 255) / 256, 256, 0, stream>>>(ei, asrc, adst, menc);
  k_ex<<<(ETOT * Bv * Hv + 255) / 256, 256, 0, stream>>>(ei, asrc, adst, menc, denom, exbuf);
  k_agg<<<Bv * Nv, 256, 0, stream>>>(h, ei, offsets, csr, exbuf, denom, bias, out);
}

// Round 2
// 286.801 us; speedup vs baseline: 1.9361x; 1.9361x over previous
//
#include <hip/hip_runtime.h>

#define Bv 2
#define Nv 5000
#define Cv 768
#define Hv 12
#define Dv 64
#define Ev 160000
#define ETOT (Ev + Nv)   // 165000 (edges + self loops)
#define HD 768
#define NEG 0.2f
#define Mv (Bv * Nv)     // 10000
#define MPAD 10112       // 79 * 128

typedef __bf16 bf16x8 __attribute__((ext_vector_type(8)));
typedef float f32x4 __attribute__((ext_vector_type(4)));

// direct-to-LDS 16B async copy
#define GLD16(gsrc, ldst)                                                      \
  __builtin_amdgcn_global_load_lds(                                            \
      (const __attribute__((address_space(1))) unsigned int*)(gsrc),           \
      (__attribute__((address_space(3))) unsigned int*)(ldst), 16, 0, 0)

// f32 -> bf16 round-to-nearest-even
__device__ __forceinline__ unsigned short f2b(float f) {
  unsigned u = __float_as_uint(f);
  return (unsigned short)((u + 0x7FFFu + ((u >> 16) & 1u)) >> 16);
}

// monotonic float<->uint encoding for atomicMax on floats (incl. negatives)
__device__ __forceinline__ unsigned enc_f(float f) {
  unsigned u = __float_as_uint(f);
  return (u & 0x80000000u) ? ~u : (u | 0x80000000u);
}
__device__ __forceinline__ float dec_f(unsigned u) {
  return (u & 0x80000000u) ? __uint_as_float(u & 0x7fffffffu) : __uint_as_float(~u);
}

// ---------------- convert x -> bf16, padded to MPAD rows -------------------
__global__ __launch_bounds__(256) void k_cvt_x(const float* __restrict__ x,
                                               unsigned short* __restrict__ xb) {
  size_t i = ((size_t)blockIdx.x * 256 + threadIdx.x) * 8;
  if (i >= (size_t)MPAD * Cv) return;
  unsigned short o[8];
  if (i < (size_t)Mv * Cv) {
    float4 v0 = *(const float4*)(x + i);
    float4 v1 = *(const float4*)(x + i + 4);
    o[0] = f2b(v0.x); o[1] = f2b(v0.y); o[2] = f2b(v0.z); o[3] = f2b(v0.w);
    o[4] = f2b(v1.x); o[5] = f2b(v1.y); o[6] = f2b(v1.z); o[7] = f2b(v1.w);
  } else {
    for (int j = 0; j < 8; ++j) o[j] = 0;
  }
  *(uint4*)(xb + i) = *(const uint4*)o;
}

// ---------------- transpose+convert W[k][n] -> Wt[n][k] bf16 ---------------
__global__ __launch_bounds__(256) void k_cvt_wt(const float* __restrict__ W,
                                                unsigned short* __restrict__ Wt) {
  __shared__ float s[32][33];
  const int k0 = blockIdx.y * 32, n0 = blockIdx.x * 32;
  const int tx = threadIdx.x, ty = threadIdx.y;  // 32 x 8
#pragma unroll
  for (int i = 0; i < 4; ++i)
    s[ty + i * 8][tx] = W[(size_t)(k0 + ty + i * 8) * HD + n0 + tx];
  __syncthreads();
#pragma unroll
  for (int i = 0; i < 4; ++i)
    Wt[(size_t)(n0 + ty + i * 8) * Cv + k0 + tx] = f2b(s[tx][ty + i * 8]);
}

// ---------------- GEMM: h[MPAD,768] = xb[MPAD,768] @ Wt^T (bf16 MFMA) ------
// 128x128 tile, BK=64, 4 waves (2x2), global_load_lds + XOR-swizzled LDS.
__global__ __launch_bounds__(256) void k_gemm_mfma(const unsigned short* __restrict__ A,
                                                   const unsigned short* __restrict__ Bt,
                                                   float* __restrict__ C) {
  __shared__ unsigned short As[128 * 64];
  __shared__ unsigned short Bs[128 * 64];
  const int t = threadIdx.x;
  const int w = t >> 6, l = t & 63;
  const int wr = w >> 1, wc = w & 1;
  const int bm = blockIdx.y * 128, bn = blockIdx.x * 128;
  const int g = l >> 4, li = l & 15;
  f32x4 acc[4][4] = {};

  const int rs = t >> 3;              // staging row within 32-row issue
  const int sl = (t & 7) ^ (rs & 7);  // pre-swizzled logical slot for source

  for (int k0 = 0; k0 < Cv; k0 += 64) {
#pragma unroll
    for (int i = 0; i < 4; ++i) {
      const int r = i * 32 + rs;
      GLD16(A + (size_t)(bm + r) * Cv + k0 + sl * 8, &As[t * 8 + i * 2048]);
      GLD16(Bt + (size_t)(bn + r) * Cv + k0 + sl * 8, &Bs[t * 8 + i * 2048]);
    }
    __syncthreads();  // drains vmcnt(0): LDS tiles ready for all waves
#pragma unroll
    for (int ks = 0; ks < 2; ++ks) {
      bf16x8 a[4], b[4];
#pragma unroll
      for (int mi = 0; mi < 4; ++mi) {
        const int row = wr * 64 + mi * 16 + li;
        const int slot = (ks * 4 + g) ^ (row & 7);
        a[mi] = *(const bf16x8*)&As[row * 64 + slot * 8];
      }
#pragma unroll
      for (int nj = 0; nj < 4; ++nj) {
        const int row = wc * 64 + nj * 16 + li;
        const int slot = (ks * 4 + g) ^ (row & 7);
        b[nj] = *(const bf16x8*)&Bs[row * 64 + slot * 8];
      }
#pragma unroll
      for (int mi = 0; mi < 4; ++mi)
#pragma unroll
        for (int nj = 0; nj < 4; ++nj)
          acc[mi][nj] = __builtin_amdgcn_mfma_f32_16x16x32_bf16(a[mi], b[nj], acc[mi][nj], 0, 0, 0);
    }
    __syncthreads();  // protect LDS before next stage
  }
  // C/D layout: col = lane&15, row = (lane>>4)*4 + reg (m89-verified)
#pragma unroll
  for (int mi = 0; mi < 4; ++mi) {
#pragma unroll
    for (int nj = 0; nj < 4; ++nj) {
      const int col = bn + wc * 64 + nj * 16 + li;
#pragma unroll
      for (int r4 = 0; r4 < 4; ++r4) {
        const int row = bm + wr * 64 + mi * 16 + g * 4 + r4;
        C[(size_t)row * HD + col] = acc[mi][nj][r4];
      }
    }
  }
}

// ---------------- attention dots: a_src/a_dst[b,n,h] = <h row, att row> ----
__global__ void k_att(const float* __restrict__ h, const float* __restrict__ att_src,
                      const float* __restrict__ att_dst, float* __restrict__ asrc,
                      float* __restrict__ adst) {
  int w = (blockIdx.x * blockDim.x + threadIdx.x) >> 6;  // one wave per (b,n,h)
  int lane = threadIdx.x & 63;
  if (w >= Bv * Nv * Hv) return;
  int hh = w % Hv;
  int bn = w / Hv;
  float hv = h[(size_t)bn * HD + hh * Dv + lane];
  float vs = hv * att_src[hh * Dv + lane];
  float vd = hv * att_dst[hh * Dv + lane];
  for (int off = 32; off; off >>= 1) {
    vs += __shfl_xor(vs, off);
    vd += __shfl_xor(vd, off);
  }
  if (lane == 0) { asrc[w] = vs; adst[w] = vd; }
}

// ---------------- CSR build ------------------------------------------------
__global__ void k_count(const int* __restrict__ ei, int* __restrict__ counts) {
  int e = blockIdx.x * blockDim.x + threadIdx.x;
  if (e >= ETOT) return;
  int dst = (e < Ev) ? ei[Ev + e] : (e - Ev);
  atomicAdd(&counts[dst], 1);
}

__global__ void k_scan(const int* __restrict__ counts, int* __restrict__ offsets) {
  __shared__ int part[256];
  const int t = threadIdx.x;
  const int chunk = (Nv + 255) / 256;  // 20
  int begin = t * chunk;
  int end = begin + chunk;
  if (end > Nv) end = Nv;
  if (begin > Nv) begin = Nv;
  int s = 0;
  for (int i = begin; i < end; ++i) s += counts[i];
  part[t] = s;
  __syncthreads();
  for (int off = 1; off < 256; off <<= 1) {
    int v = (t >= off) ? part[t - off] : 0;
    __syncthreads();
    part[t] += v;
    __syncthreads();
  }
  int run = (t == 0) ? 0 : part[t - 1];
  for (int i = begin; i < end; ++i) {
    offsets[i] = run;
    run += counts[i];
  }
  if (t == 0) offsets[Nv] = ETOT;
}

__global__ void k_scatter(const int* __restrict__ ei, const int* __restrict__ offsets,
                          int* __restrict__ cursor, int* __restrict__ csr) {
  int e = blockIdx.x * blockDim.x + threadIdx.x;
  if (e >= ETOT) return;
  int dst = (e < Ev) ? ei[Ev + e] : (e - Ev);
  int pos = atomicAdd(&cursor[dst], 1);
  csr[offsets[dst] + pos] = e;
}

// ---------------- softmax: segment max then exp+denominator ---------------
__global__ void k_emax(const int* __restrict__ ei, const float* __restrict__ asrc,
                       const float* __restrict__ adst, unsigned* __restrict__ menc) {
  int idx = blockIdx.x * blockDim.x + threadIdx.x;
  if (idx >= ETOT * Bv * Hv) return;
  int e = idx / (Bv * Hv);
  int r = idx % (Bv * Hv);
  int b = r / Hv, hh = r % Hv;
  int src = (e < Ev) ? ei[e] : (e - Ev);
  int dst = (e < Ev) ? ei[Ev + e] : (e - Ev);
  float v = asrc[((size_t)b * Nv + src) * Hv + hh] + adst[((size_t)b * Nv + dst) * Hv + hh];
  v = (v > 0.f) ? v : NEG * v;
  atomicMax(&menc[((size_t)b * Nv + dst) * Hv + hh], enc_f(v));
}

__global__ void k_ex(const int* __restrict__ ei, const float* __restrict__ asrc,
                     const float* __restrict__ adst, const unsigned* __restrict__ menc,
                     float* __restrict__ denom, float* __restrict__ exbuf) {
  int idx = blockIdx.x * blockDim.x + threadIdx.x;
  if (idx >= ETOT * Bv * Hv) return;
  int e = idx / (Bv * Hv);
  int r = idx % (Bv * Hv);
  int b = r / Hv, hh = r % Hv;
  int src = (e < Ev) ? ei[e] : (e - Ev);
  int dst = (e < Ev) ? ei[Ev + e] : (e - Ev);
  size_t di = ((size_t)b * Nv + dst) * Hv + hh;
  float v = asrc[((size_t)b * Nv + src) * Hv + hh] + adst[di];
  v = (v > 0.f) ? v : NEG * v;
  float ex = expf(v - dec_f(menc[di]));
  exbuf[idx] = ex;  // layout [e][b][h] == idx
  atomicAdd(&denom[di], ex);
}

// ---------------- aggregation: out[b,n,:] = sum_e alpha * h[b,src,:] ------
__global__ __launch_bounds__(256) void k_agg(const float* __restrict__ h,
                                             const int* __restrict__ ei,
                                             const int* __restrict__ offsets,
                                             const int* __restrict__ csr,
                                             const float* __restrict__ exbuf,
                                             const float* __restrict__ denom,
                                             const float* __restrict__ bias,
                                             float* __restrict__ out) {
  const int bn = blockIdx.x;  // b*Nv + n
  const int b = bn / Nv, n = bn % Nv;
  const int t = threadIdx.x;
  __shared__ float s_den[Hv];
  __shared__ float s_ex[16][Hv];
  __shared__ int s_src[16];
  if (t < Hv) s_den[t] = denom[(size_t)bn * Hv + t];
  __syncthreads();
  const int h0 = t >> 6;  // thread covers dims t, t+256, t+512 -> heads h0, h0+4, h0+8
  float invd[3];
  invd[0] = 1.0f / (s_den[h0] + 1e-16f);
  invd[1] = 1.0f / (s_den[h0 + 4] + 1e-16f);
  invd[2] = 1.0f / (s_den[h0 + 8] + 1e-16f);
  float acc[3] = {0.f, 0.f, 0.f};
  const int beg = offsets[n], endv = offsets[n + 1];
  for (int base = beg; base < endv; base += 16) {
    const int cnt = min(16, endv - base);
    if (t < cnt) {
      int e = csr[base + t];
      s_src[t] = (e < Ev) ? ei[e] : (e - Ev);
    }
    if (t < cnt * Hv) {
      int i = t / Hv, hh = t % Hv;
      int e = csr[base + i];
      s_ex[i][hh] = exbuf[(size_t)e * (Bv * Hv) + b * Hv + hh];
    }
    __syncthreads();
    for (int i = 0; i < cnt; ++i) {
      const float* hp = h + ((size_t)b * Nv + s_src[i]) * HD;
      float w0 = s_ex[i][h0] * invd[0];
      float w1 = s_ex[i][h0 + 4] * invd[1];
      float w2 = s_ex[i][h0 + 8] * invd[2];
      acc[0] = fmaf(w0, hp[t], acc[0]);
      acc[1] = fmaf(w1, hp[t + 256], acc[1]);
      acc[2] = fmaf(w2, hp[t + 512], acc[2]);
    }
    __syncthreads();
  }
  size_t ob = (size_t)bn * HD;
  out[ob + t] = acc[0] + bias[t];
  out[ob + t + 256] = acc[1] + bias[t + 256];
  out[ob + t + 512] = acc[2] + bias[t + 512];
}

extern "C" void kernel_launch(void* const* d_in, const int* in_sizes, int n_in,
                              void* d_out, int out_size, void* d_ws, size_t ws_size,
                              hipStream_t stream) {
  const float* x = (const float*)d_in[0];
  const float* W = (const float*)d_in[1];
  const float* att_src = (const float*)d_in[2];
  const float* att_dst = (const float*)d_in[3];
  const float* bias = (const float*)d_in[4];
  const int* ei = (const int*)d_in[5];
  float* out = (float*)d_out;

  // workspace layout (floats unless noted); xbf aliases exbuf (disjoint lifetimes)
  float* ws = (float*)d_ws;
  float* h = ws;                                         // MPAD*768 = 7,766,016 f32
  float* region2 = h + (size_t)MPAD * HD;                // max(xbf, exbuf) = 3,960,000 f32
  unsigned short* xbf = (unsigned short*)region2;        // MPAD*768 bf16 (GEMM input)
  float* exbuf = region2;                                // ETOT*B*H f32 (post-GEMM)
  unsigned short* wt = (unsigned short*)(region2 + (size_t)ETOT * Bv * Hv);  // 768*768 bf16
  float* asrc = (float*)(wt + (size_t)HD * Cv);          // 120,000
  float* adst = asrc + (size_t)Bv * Nv * Hv;             // 120,000
  unsigned* menc = (unsigned*)(adst + (size_t)Bv * Nv * Hv);  // 120,000
  float* denom = ((float*)menc) + (size_t)Bv * Nv * Hv;       // 120,000
  int* counts = (int*)(denom + (size_t)Bv * Nv * Hv);    // Nv
  int* cursor = counts + Nv;                             // Nv
  int* offsets = cursor + Nv;                            // Nv+1
  int* csr = offsets + Nv + 1;                           // ETOT

  hipMemsetAsync(menc, 0, sizeof(float) * 2 * (size_t)Bv * Nv * Hv, stream);
  hipMemsetAsync(counts, 0, sizeof(int) * 2 * Nv, stream);

  k_cvt_x<<<(int)(((size_t)MPAD * HD / 8 + 255) / 256), 256, 0, stream>>>(x, xbf);
  k_cvt_wt<<<dim3(HD / 32, Cv / 32), dim3(32, 8), 0, stream>>>(W, wt);
  k_gemm_mfma<<<dim3(HD / 128, MPAD / 128), 256, 0, stream>>>(xbf, wt, h);
  k_att<<<(Bv * Nv * Hv + 3) / 4, 256, 0, stream>>>(h, att_src, att_dst, asrc, adst);
  k_count<<<(ETOT + 255) / 256, 256, 0, stream>>>(ei, counts);
  k_scan<<<1, 256, 0, stream>>>(counts, offsets);
  k_scatter<<<(ETOT + 255) / 256, 256, 0, stream>>>(ei, offsets, cursor, csr);
  k_emax<<<(ETOT * Bv * Hv + 255) / 256, 256, 0, stream>>>(ei, asrc, adst, menc);
  k_ex<<<(ETOT * Bv * Hv + 255) / 256, 256, 0, stream>>>(ei, asrc, adst, menc, denom, exbuf);
  k_agg<<<Bv * Nv, 256, 0, stream>>>(h, ei, offsets, csr, exbuf, denom, bias, out);
}

// Round 3
// 224.617 us; speedup vs baseline: 2.4721x; 1.2768x over previous
//
#include <hip/hip_runtime.h>

#define Bv 2
#define Nv 5000
#define Cv 768
#define Hv 12
#define Dv 64
#define Ev 160000
#define ETOT (Ev + Nv)   // 165000 (edges + self loops)
#define HD 768
#define NEG 0.2f
#define Mv (Bv * Nv)     // 10000
#define MPAD 10112       // 79 * 128

typedef __bf16 bf16x8 __attribute__((ext_vector_type(8)));
typedef float f32x4 __attribute__((ext_vector_type(4)));

// direct-to-LDS 16B async copy
#define GLD16(gsrc, ldst)                                                      \
  __builtin_amdgcn_global_load_lds(                                            \
      (const __attribute__((address_space(1))) unsigned int*)(gsrc),           \
      (__attribute__((address_space(3))) unsigned int*)(ldst), 16, 0, 0)

// f32 -> bf16 round-to-nearest-even
__device__ __forceinline__ unsigned short f2b(float f) {
  unsigned u = __float_as_uint(f);
  return (unsigned short)((u + 0x7FFFu + ((u >> 16) & 1u)) >> 16);
}
__device__ __forceinline__ float b2f(unsigned short b) {
  return __uint_as_float((unsigned)b << 16);
}

// ---------------- convert x -> bf16, padded to MPAD rows -------------------
__global__ __launch_bounds__(256) void k_cvt_x(const float* __restrict__ x,
                                               unsigned short* __restrict__ xb) {
  size_t i = ((size_t)blockIdx.x * 256 + threadIdx.x) * 8;
  if (i >= (size_t)MPAD * Cv) return;
  unsigned short o[8];
  if (i < (size_t)Mv * Cv) {
    float4 v0 = *(const float4*)(x + i);
    float4 v1 = *(const float4*)(x + i + 4);
    o[0] = f2b(v0.x); o[1] = f2b(v0.y); o[2] = f2b(v0.z); o[3] = f2b(v0.w);
    o[4] = f2b(v1.x); o[5] = f2b(v1.y); o[6] = f2b(v1.z); o[7] = f2b(v1.w);
  } else {
    for (int j = 0; j < 8; ++j) o[j] = 0;
  }
  *(uint4*)(xb + i) = *(const uint4*)o;
}

// ---------------- transpose+convert W[k][n] -> Wt[n][k] bf16 ---------------
__global__ __launch_bounds__(256) void k_cvt_wt(const float* __restrict__ W,
                                                unsigned short* __restrict__ Wt) {
  __shared__ float s[32][33];
  const int k0 = blockIdx.y * 32, n0 = blockIdx.x * 32;
  const int tx = threadIdx.x, ty = threadIdx.y;  // 32 x 8
#pragma unroll
  for (int i = 0; i < 4; ++i)
    s[ty + i * 8][tx] = W[(size_t)(k0 + ty + i * 8) * HD + n0 + tx];
  __syncthreads();
#pragma unroll
  for (int i = 0; i < 4; ++i)
    Wt[(size_t)(n0 + ty + i * 8) * Cv + k0 + tx] = f2b(s[tx][ty + i * 8]);
}

// ---------------- GEMM: h2[MPAD,768] = xb @ Wt^T (bf16 MFMA, bf16 out) -----
// 128x128 tile, BK=64, 4 waves (2x2), global_load_lds + XOR-swizzled LDS.
__global__ __launch_bounds__(256) void k_gemm_mfma(const unsigned short* __restrict__ A,
                                                   const unsigned short* __restrict__ Bt,
                                                   unsigned short* __restrict__ C) {
  __shared__ unsigned short As[128 * 64];
  __shared__ unsigned short Bs[128 * 64];
  const int t = threadIdx.x;
  const int w = t >> 6, l = t & 63;
  const int wr = w >> 1, wc = w & 1;
  const int bm = blockIdx.y * 128, bn = blockIdx.x * 128;
  const int g = l >> 4, li = l & 15;
  f32x4 acc[4][4] = {};

  const int rs = t >> 3;              // staging row within 32-row issue
  const int sl = (t & 7) ^ (rs & 7);  // pre-swizzled logical slot for source

  for (int k0 = 0; k0 < Cv; k0 += 64) {
#pragma unroll
    for (int i = 0; i < 4; ++i) {
      const int r = i * 32 + rs;
      GLD16(A + (size_t)(bm + r) * Cv + k0 + sl * 8, &As[t * 8 + i * 2048]);
      GLD16(Bt + (size_t)(bn + r) * Cv + k0 + sl * 8, &Bs[t * 8 + i * 2048]);
    }
    __syncthreads();  // drains vmcnt(0): LDS tiles ready for all waves
#pragma unroll
    for (int ks = 0; ks < 2; ++ks) {
      bf16x8 a[4], b[4];
#pragma unroll
      for (int mi = 0; mi < 4; ++mi) {
        const int row = wr * 64 + mi * 16 + li;
        const int slot = (ks * 4 + g) ^ (row & 7);
        a[mi] = *(const bf16x8*)&As[row * 64 + slot * 8];
      }
#pragma unroll
      for (int nj = 0; nj < 4; ++nj) {
        const int row = wc * 64 + nj * 16 + li;
        const int slot = (ks * 4 + g) ^ (row & 7);
        b[nj] = *(const bf16x8*)&Bs[row * 64 + slot * 8];
      }
#pragma unroll
      for (int mi = 0; mi < 4; ++mi)
#pragma unroll
        for (int nj = 0; nj < 4; ++nj)
          acc[mi][nj] = __builtin_amdgcn_mfma_f32_16x16x32_bf16(a[mi], b[nj], acc[mi][nj], 0, 0, 0);
    }
    __syncthreads();  // protect LDS before next stage
  }
  // C/D layout: col = lane&15, row = (lane>>4)*4 + reg (m89-verified)
#pragma unroll
  for (int mi = 0; mi < 4; ++mi) {
#pragma unroll
    for (int nj = 0; nj < 4; ++nj) {
      const int col = bn + wc * 64 + nj * 16 + li;
#pragma unroll
      for (int r4 = 0; r4 < 4; ++r4) {
        const int row = bm + wr * 64 + mi * 16 + g * 4 + r4;
        C[(size_t)row * HD + col] = f2b(acc[mi][nj][r4]);
      }
    }
  }
}

// ---------------- attention dots from bf16 h -------------------------------
__global__ void k_att(const unsigned short* __restrict__ h2, const float* __restrict__ att_src,
                      const float* __restrict__ att_dst, float* __restrict__ asrc,
                      float* __restrict__ adst) {
  int w = (blockIdx.x * blockDim.x + threadIdx.x) >> 6;  // one wave per (b,n,h)
  int lane = threadIdx.x & 63;
  if (w >= Bv * Nv * Hv) return;
  int hh = w % Hv;
  int bn = w / Hv;
  float hv = b2f(h2[(size_t)bn * HD + hh * Dv + lane]);
  float vs = hv * att_src[hh * Dv + lane];
  float vd = hv * att_dst[hh * Dv + lane];
  for (int off = 32; off; off >>= 1) {
    vs += __shfl_xor(vs, off);
    vd += __shfl_xor(vd, off);
  }
  if (lane == 0) { asrc[w] = vs; adst[w] = vd; }
}

// ---------------- CSR build ------------------------------------------------
__global__ void k_count(const int* __restrict__ ei, int* __restrict__ counts) {
  int e = blockIdx.x * blockDim.x + threadIdx.x;
  if (e >= ETOT) return;
  int dst = (e < Ev) ? ei[Ev + e] : (e - Ev);
  atomicAdd(&counts[dst], 1);
}

__global__ void k_scan(const int* __restrict__ counts, int* __restrict__ offsets) {
  __shared__ int part[256];
  const int t = threadIdx.x;
  const int chunk = (Nv + 255) / 256;  // 20
  int begin = t * chunk;
  int end = begin + chunk;
  if (end > Nv) end = Nv;
  if (begin > Nv) begin = Nv;
  int s = 0;
  for (int i = begin; i < end; ++i) s += counts[i];
  part[t] = s;
  __syncthreads();
  for (int off = 1; off < 256; off <<= 1) {
    int v = (t >= off) ? part[t - off] : 0;
    __syncthreads();
    part[t] += v;
    __syncthreads();
  }
  int run = (t == 0) ? 0 : part[t - 1];
  for (int i = begin; i < end; ++i) {
    offsets[i] = run;
    run += counts[i];
  }
  if (t == 0) offsets[Nv] = ETOT;
}

__global__ void k_scatter(const int* __restrict__ ei, const int* __restrict__ offsets,
                          int* __restrict__ cursor, int* __restrict__ csr) {
  int e = blockIdx.x * blockDim.x + threadIdx.x;
  if (e >= ETOT) return;
  int dst = (e < Ev) ? ei[Ev + e] : (e - Ev);
  int pos = atomicAdd(&cursor[dst], 1);
  csr[offsets[dst] + pos] = e;
}

// ---------------- softmax over each dst's edge list (no atomics) -----------
// thread t -> (b,n,h); walks CSR twice: max pass, then exp+sum pass.
__global__ __launch_bounds__(256) void k_soft(const int* __restrict__ ei,
                                              const int* __restrict__ offsets,
                                              const int* __restrict__ csr,
                                              const float* __restrict__ asrc,
                                              const float* __restrict__ adst,
                                              float* __restrict__ exbuf,
                                              float* __restrict__ invd) {
  int t = blockIdx.x * 256 + threadIdx.x;
  if (t >= Bv * Nv * Hv) return;
  const int hh = t % Hv;
  const int bn = t / Hv;
  const int b = bn / Nv, n = bn % Nv;
  const int beg = offsets[n], endv = offsets[n + 1];
  const float ad = adst[t];
  float m = -1e30f;
  for (int i = beg; i < endv; ++i) {
    int e = csr[i];
    int src = (e < Ev) ? ei[e] : (e - Ev);
    float v = asrc[((size_t)b * Nv + src) * Hv + hh] + ad;
    v = (v > 0.f) ? v : NEG * v;
    m = fmaxf(m, v);
  }
  float s = 0.f;
  for (int i = beg; i < endv; ++i) {
    int e = csr[i];
    int src = (e < Ev) ? ei[e] : (e - Ev);
    float v = asrc[((size_t)b * Nv + src) * Hv + hh] + ad;
    v = (v > 0.f) ? v : NEG * v;
    float ex = expf(v - m);
    exbuf[(size_t)e * (Bv * Hv) + b * Hv + hh] = ex;
    s += ex;
  }
  invd[t] = 1.0f / (s + 1e-16f);
}

// ---------------- aggregation: out[b,n,:] = sum_e alpha * h[b,src,:] ------
// 192 threads; thread owns 4 contiguous dims (one ushort4 per edge), head=t>>4.
__global__ __launch_bounds__(192) void k_agg(const unsigned short* __restrict__ h2,
                                             const int* __restrict__ ei,
                                             const int* __restrict__ offsets,
                                             const int* __restrict__ csr,
                                             const float* __restrict__ exbuf,
                                             const float* __restrict__ invd,
                                             const float* __restrict__ bias,
                                             float* __restrict__ out) {
  const int bn = blockIdx.x;  // b*Nv + n
  const int b = bn / Nv, n = bn % Nv;
  const int t = threadIdx.x;
  __shared__ float s_inv[Hv];
  __shared__ float s_ex[16][Hv];
  __shared__ int s_src[16];
  if (t < Hv) s_inv[t] = invd[(size_t)bn * Hv + t];
  __syncthreads();
  const int hh = t >> 4;  // 4*t/64: single head per thread
  float acc0 = 0.f, acc1 = 0.f, acc2 = 0.f, acc3 = 0.f;
  const int beg = offsets[n], endv = offsets[n + 1];
  for (int base = beg; base < endv; base += 16) {
    const int cnt = min(16, endv - base);
    if (t < cnt) {
      int e = csr[base + t];
      s_src[t] = (e < Ev) ? ei[e] : (e - Ev);
    }
    if (t < cnt * Hv) {
      int i = t / Hv, hj = t % Hv;
      int e = csr[base + i];
      s_ex[i][hj] = exbuf[(size_t)e * (Bv * Hv) + b * Hv + hj] * s_inv[hj];
    }
    __syncthreads();
    for (int i = 0; i < cnt; ++i) {
      const unsigned short* hp = h2 + ((size_t)b * Nv + s_src[i]) * HD + t * 4;
      ushort4 v = *(const ushort4*)hp;
      const float w = s_ex[i][hh];
      acc0 = fmaf(w, b2f(v.x), acc0);
      acc1 = fmaf(w, b2f(v.y), acc1);
      acc2 = fmaf(w, b2f(v.z), acc2);
      acc3 = fmaf(w, b2f(v.w), acc3);
    }
    __syncthreads();
  }
  float4 o;
  o.x = acc0 + bias[t * 4 + 0];
  o.y = acc1 + bias[t * 4 + 1];
  o.z = acc2 + bias[t * 4 + 2];
  o.w = acc3 + bias[t * 4 + 3];
  *(float4*)(out + (size_t)bn * HD + t * 4) = o;
}

extern "C" void kernel_launch(void* const* d_in, const int* in_sizes, int n_in,
                              void* d_out, int out_size, void* d_ws, size_t ws_size,
                              hipStream_t stream) {
  const float* x = (const float*)d_in[0];
  const float* W = (const float*)d_in[1];
  const float* att_src = (const float*)d_in[2];
  const float* att_dst = (const float*)d_in[3];
  const float* bias = (const float*)d_in[4];
  const int* ei = (const int*)d_in[5];
  float* out = (float*)d_out;

  // workspace layout; xbf aliases exbuf (disjoint lifetimes)
  unsigned short* h2 = (unsigned short*)d_ws;            // MPAD*768 bf16
  float* region2 = (float*)(h2 + (size_t)MPAD * HD);     // max(xbf bf16, exbuf f32)
  unsigned short* xbf = (unsigned short*)region2;        // MPAD*768 bf16 (GEMM input)
  float* exbuf = region2;                                // ETOT*B*H f32 (post-GEMM)
  unsigned short* wt = (unsigned short*)(region2 + (size_t)ETOT * Bv * Hv);  // 768*768 bf16
  float* asrc = (float*)(wt + (size_t)HD * Cv);          // 120,000
  float* adst = asrc + (size_t)Bv * Nv * Hv;             // 120,000
  float* invd = adst + (size_t)Bv * Nv * Hv;             // 120,000
  int* counts = (int*)(invd + (size_t)Bv * Nv * Hv);     // Nv
  int* cursor = counts + Nv;                             // Nv
  int* offsets = cursor + Nv;                            // Nv+1
  int* csr = offsets + Nv + 1;                           // ETOT

  hipMemsetAsync(counts, 0, sizeof(int) * 2 * Nv, stream);

  k_cvt_x<<<(int)(((size_t)MPAD * HD / 8 + 255) / 256), 256, 0, stream>>>(x, xbf);
  k_cvt_wt<<<dim3(HD / 32, Cv / 32), dim3(32, 8), 0, stream>>>(W, wt);
  k_gemm_mfma<<<dim3(HD / 128, MPAD / 128), 256, 0, stream>>>(xbf, wt, h2);
  k_att<<<(Bv * Nv * Hv + 3) / 4, 256, 0, stream>>>(h2, att_src, att_dst, asrc, adst);
  k_count<<<(ETOT + 255) / 256, 256, 0, stream>>>(ei, counts);
  k_scan<<<1, 256, 0, stream>>>(counts, offsets);
  k_scatter<<<(ETOT + 255) / 256, 256, 0, stream>>>(ei, offsets, cursor, csr);
  k_soft<<<(Bv * Nv * Hv + 255) / 256, 256, 0, stream>>>(ei, offsets, csr, asrc, adst, exbuf, invd);
  k_agg<<<Bv * Nv, 192, 0, stream>>>(h2, ei, offsets, csr, exbuf, invd, bias, out);
}